// Round 12
// baseline (167.736 us; speedup 1.0000x reference)
//
#include <hip/hip_runtime.h>
#include <math.h>

// e0 = 4*((1/3)^12 - (1/3)^6); 0.5*pe = 2*(c12 - c6) - 0.5*e0
static constexpr float HALF_NEG_E0 = 2.739720872e-3f; // -0.5*e0

#define T 256           // threads per block
#define B1 2500         // blocks for p3
#define SHIFT 10
#define BK 1024         // nodes per bucket (lid fits in 10 bits)
#define Q 8             // gather sub-blocks per bucket in p4a
#define RPQ_MAX 352     // max runs per p4a block (ceil(B1/Q)=313)
#define FPSCALE 512.0f  // |f| <= 59.5 -> |int| <= 30450 < 32767
#define INV_FPSCALE (1.0f / 512.0f)

// ---- Phase 3: deterministic staging (NO global atomics, NO memsets).
//      R12: dead s_bkt removed; WAVE-PRIVATE histograms+cursors lcur[4][NB]
//      (LDS same-address atomic serialization /4); 512-value bucket-major
//      shuffle scan; int4 flush. dst+bv register-cached (single global read).
__global__ __launch_bounds__(T)
void p3_fused(const float* __restrict__ bv, const int* __restrict__ dst,
              int* __restrict__ bmap, int2* __restrict__ sorted,
              float* __restrict__ eblk, int E, int NB, int GPB, int capb)
{
    extern __shared__ int smem[];
    int2* s_ent = (int2*)smem;                    // [capb]
    int*  lcur  = smem + 2 * capb;                // [4][NB] wave-private
    __shared__ int   wtot[4];
    __shared__ float wsum[4];

    const int r = blockIdx.x;
    const int t = threadIdx.x;
    const int wid = t >> 6, lane = t & 63;

    const int G  = (E + 3) >> 2;
    const int gs = r * GPB;
    const int ge = min(G, gs + GPB);
    const int4*   __restrict__ d4  = (const int4*)dst;
    const float4* __restrict__ bv4 = (const float4*)bv;

    // up to 3 groups per thread (launcher guards GPB <= 3*T)
    const int g0 = gs + t, g1 = g0 + T, g2 = g1 + T;
    const bool v0 = g0 < ge, v1 = g1 < ge, v2 = g2 < ge;
    const bool f0 = v0 && ((g0 << 2) + 3 < E);
    const bool f1 = v1 && ((g1 << 2) + 3 < E);
    const bool f2 = v2 && ((g2 << 2) + 3 < E);

    // ---- issue ALL global loads up front: dst, then bv ---------------------
    int4 dA, dB, dC;
    if (f0) dA = d4[g0];
    if (f1) dB = d4[g1];
    if (f2) dC = d4[g2];
    float4 aA, bA, cA, aB, bB, cB, aC, bC, cC;
    if (f0) { aA = bv4[3 * g0]; bA = bv4[3 * g0 + 1]; cA = bv4[3 * g0 + 2]; }
    if (f1) { aB = bv4[3 * g1]; bB = bv4[3 * g1 + 1]; cB = bv4[3 * g1 + 2]; }
    if (f2) { aC = bv4[3 * g2]; bC = bv4[3 * g2 + 1]; cC = bv4[3 * g2 + 2]; }

    for (int i = t; i < 4 * NB; i += T) lcur[i] = 0;
    __syncthreads();

    // ---- pass A: histogram into this wave's private copy -------------------
    int* myc = lcur + wid * NB;
    if (f0) {
        atomicAdd(&myc[((unsigned)dA.x) >> SHIFT], 1);
        atomicAdd(&myc[((unsigned)dA.y) >> SHIFT], 1);
        atomicAdd(&myc[((unsigned)dA.z) >> SHIFT], 1);
        atomicAdd(&myc[((unsigned)dA.w) >> SHIFT], 1);
    } else if (v0) {
        for (int e = g0 << 2; e < E; ++e)
            atomicAdd(&myc[((unsigned)dst[e]) >> SHIFT], 1);
    }
    if (f1) {
        atomicAdd(&myc[((unsigned)dB.x) >> SHIFT], 1);
        atomicAdd(&myc[((unsigned)dB.y) >> SHIFT], 1);
        atomicAdd(&myc[((unsigned)dB.z) >> SHIFT], 1);
        atomicAdd(&myc[((unsigned)dB.w) >> SHIFT], 1);
    } else if (v1) {
        for (int e = g1 << 2; e < E; ++e)
            atomicAdd(&myc[((unsigned)dst[e]) >> SHIFT], 1);
    }
    if (f2) {
        atomicAdd(&myc[((unsigned)dC.x) >> SHIFT], 1);
        atomicAdd(&myc[((unsigned)dC.y) >> SHIFT], 1);
        atomicAdd(&myc[((unsigned)dC.z) >> SHIFT], 1);
        atomicAdd(&myc[((unsigned)dC.w) >> SHIFT], 1);
    } else if (v2) {
        for (int e = g2 << 2; e < E; ++e)
            atomicAdd(&myc[((unsigned)dst[e]) >> SHIFT], 1);
    }
    __syncthreads();

    // ---- exclusive scan over 4*NB values, bucket-major j = b*4 + w ---------
    // 2 values per thread; wave shuffle scan + 4-entry combine.
    {
        const int j0 = 2 * t, j1 = 2 * t + 1;
        const int M  = 4 * NB;
        int va = (j0 < M) ? lcur[(j0 & 3) * NB + (j0 >> 2)] : 0;
        int vb = (j1 < M) ? lcur[(j1 & 3) * NB + (j1 >> 2)] : 0;
        int s = va + vb;
        int incl = s;
#pragma unroll
        for (int off = 1; off < 64; off <<= 1) {
            int u = __shfl_up(incl, off, 64);
            if (lane >= off) incl += u;
        }
        if (lane == 63) wtot[wid] = incl;
        __syncthreads();
        int wpre = 0;
#pragma unroll
        for (int w = 0; w < 4; ++w) wpre += (w < wid) ? wtot[w] : 0;
        int ex0 = wpre + incl - s;
        if (j0 < M) lcur[(j0 & 3) * NB + (j0 >> 2)] = ex0;
        if (j1 < M) lcur[(j1 & 3) * NB + (j1 >> 2)] = ex0 + va;
    }
    __syncthreads();

    // ---- write run directory from bucket starts (w=0 slots) ----------------
    const int nloc = max(0, min(E, ge << 2) - (gs << 2));
    if (t < NB) {
        int st = lcur[t];                         // ex(b, w=0) = region start
        int en = (t + 1 < NB) ? lcur[t + 1] : nloc;
        bmap[(size_t)r * NB + t] = st | ((en - st) << 16);
    }
    __syncthreads();

    // ---- pass B: compute + stage via wave-private cursors ------------------
    float esum = 0.0f;

    auto edge1 = [&](float x, float y, float z, int node) {
        float r2  = x * x + y * y + z * z;
        float inv = 1.0f / r2;
        float c6  = inv * inv * inv;
        float c12 = c6 * c6;
        esum += 2.0f * (c12 - c6) + HALF_NEG_E0;
        float fs = -24.0f * (2.0f * c12 - c6) * inv * FPSCALE;
        int ix = __float2int_rn(fs * x);
        int iy = __float2int_rn(fs * y);
        int iz = __float2int_rn(fs * z);
        int b  = ((unsigned)node) >> SHIFT;
        int slot = atomicAdd(&myc[b], 1);         // wave-private cursor
        s_ent[slot] = make_int2((ix & 0xffff) | (iy << 16),
                                (iz & 0xffff) | ((node & (BK - 1)) << 16));
    };

    if (f0) {
        edge1(aA.x, aA.y, aA.z, dA.x);
        edge1(aA.w, bA.x, bA.y, dA.y);
        edge1(bA.z, bA.w, cA.x, dA.z);
        edge1(cA.y, cA.z, cA.w, dA.w);
    } else if (v0) {
        for (int e = g0 << 2; e < E; ++e)
            edge1(bv[3 * e], bv[3 * e + 1], bv[3 * e + 2], dst[e]);
    }
    if (f1) {
        edge1(aB.x, aB.y, aB.z, dB.x);
        edge1(aB.w, bB.x, bB.y, dB.y);
        edge1(bB.z, bB.w, cB.x, dB.z);
        edge1(cB.y, cB.z, cB.w, dB.w);
    } else if (v1) {
        for (int e = g1 << 2; e < E; ++e)
            edge1(bv[3 * e], bv[3 * e + 1], bv[3 * e + 2], dst[e]);
    }
    if (f2) {
        edge1(aC.x, aC.y, aC.z, dC.x);
        edge1(aC.w, bC.x, bC.y, dC.y);
        edge1(bC.z, bC.w, cC.x, dC.z);
        edge1(cC.y, cC.z, cC.w, dC.w);
    } else if (v2) {
        for (int e = g2 << 2; e < E; ++e)
            edge1(bv[3 * e], bv[3 * e + 1], bv[3 * e + 2], dst[e]);
    }
    __syncthreads();

    // ---- flush: int4 pairs, contiguous coalesced write to own region -------
    {
        const int nh = nloc >> 1;
        const int4* se4 = (const int4*)s_ent;
        int4* so4 = (int4*)(sorted + (size_t)r * capb);   // capb even -> 16B
        for (int i = t; i < nh; i += T) so4[i] = se4[i];
        if ((nloc & 1) && t == 0)
            sorted[(size_t)r * capb + nloc - 1] = s_ent[nloc - 1];
    }

    // ---- energy: wave shuffle -> LDS -> one plain store per block ----------
#pragma unroll
    for (int off = 32; off > 0; off >>= 1)
        esum += __shfl_down(esum, off, 64);
    if (lane == 0) wsum[wid] = esum;
    __syncthreads();
    if (t == 0) {
        float s = 0.0f;
        for (int w = 0; w < 4; ++w) s += wsum[w];
        eblk[r] = s;
    }
}

// ---- Phase 4a: bucket-major partial reduce over a run-subrange -------------
// (unchanged from R11, verified) Quarter-wave-per-run gather, packed u64 LDS
// accumulate, deterministic int partials.
__global__ __launch_bounds__(T)
void p4a_partial(const int2* __restrict__ sorted, const int* __restrict__ bmap,
                 unsigned long long* __restrict__ partXY, int* __restrict__ partZ,
                 int NB, int nblk, int capb, int rpq)
{
    __shared__ unsigned long long accXY[BK];      // 8 KB
    __shared__ int accZ[BK];                      // 4 KB
    __shared__ int runsL[RPQ_MAX];                // run directory slice

    const int b = blockIdx.x / Q;
    const int q = blockIdx.x - b * Q;
    const int t = threadIdx.x;

    const int rbeg = q * rpq;
    const int rend = min(nblk, rbeg + rpq);
    const int nr   = rend - rbeg;

    for (int i = t; i < BK; i += T) { accXY[i] = 0ull; accZ[i] = 0; }
    for (int i = t; i < nr; i += T) runsL[i] = bmap[(size_t)(rbeg + i) * NB + b];
    __syncthreads();

    const int wid  = t >> 6;
    const int lane = t & 63;
    const int sub  = lane >> 4;   // quarter-wave id 0..3
    const int l16  = lane & 15;

    for (int rr = 4 * wid; rr < nr; rr += 16) {
        const int ri = rr + sub;
        if (ri < nr) {
            const int m   = runsL[ri];
            const int cnt = m >> 16;
            const int2* src = sorted + (size_t)(rbeg + ri) * capb + (m & 0xffff);
            for (int c = l16; c < cnt; c += 16) {
                int2 v = src[c];
                int lid = ((unsigned)v.y) >> 16;
                unsigned long long p =
                    ((unsigned long long)(unsigned)(v.x >> 16) << 32)
                  + (unsigned long long)(long long)(int)(short)(v.x & 0xffff);
                atomicAdd(&accXY[lid], p);
                atomicAdd(&accZ[lid], (int)(short)(v.y & 0xffff));
            }
        }
    }
    __syncthreads();
    unsigned long long* PX = partXY + (size_t)blockIdx.x * BK;
    int*                PZ = partZ  + (size_t)blockIdx.x * BK;
    for (int i = t; i < BK; i += T) { PX[i] = accXY[i]; PZ[i] = accZ[i]; }
}

// ---- Phase 4b: merge Q packed partials per node, decode, write outputs -----
// (unchanged from R11, verified)
__global__ __launch_bounds__(T)
void p4b_merge(const unsigned long long* __restrict__ partXY,
               const int* __restrict__ partZ, const float* __restrict__ eblk,
               float* __restrict__ forces, float* __restrict__ analytic,
               float* __restrict__ energy, int N, int nblk)
{
    __shared__ float ws[T / 64];
    const int t = threadIdx.x;

    if (blockIdx.x == 0) {
        float es = 0.0f;
        for (int i = t; i < nblk; i += T) es += eblk[i];
#pragma unroll
        for (int off = 32; off > 0; off >>= 1)
            es += __shfl_down(es, off, 64);
        if ((t & 63) == 0) ws[t >> 6] = es;
        __syncthreads();
        if (t == 0) {
            float s = 0.0f;
            for (int w = 0; w < T / 64; ++w) s += ws[w];
            energy[0] = s;
        }
    }

    const int node = blockIdx.x * T + t;
    if (node >= N) return;
    const int b   = node >> SHIFT;
    const int lid = node & (BK - 1);
    const unsigned long long* PX = partXY + ((size_t)b * Q) * BK + lid;
    const int*                PZ = partZ  + ((size_t)b * Q) * BK + lid;
    unsigned long long sxy = 0ull; int sz = 0;
#pragma unroll
    for (int qq = 0; qq < Q; ++qq) {
        sxy += PX[(size_t)qq * BK];
        sz  += PZ[(size_t)qq * BK];
    }
    int sx = (int)(unsigned)(sxy & 0xffffffffull);
    int sy = (int)(unsigned)(sxy >> 32) + (sx < 0 ? 1 : 0);
    float vx = (float)sx * INV_FPSCALE;
    float vy = (float)sy * INV_FPSCALE;
    float vz = (float)sz * INV_FPSCALE;
    analytic[3 * node + 0] = vx;
    analytic[3 * node + 1] = vy;
    analytic[3 * node + 2] = vz;
    forces[3 * node + 0] = -0.5f * vx;
    forces[3 * node + 1] = -0.5f * vy;
    forces[3 * node + 2] = -0.5f * vz;
}

// ---------------- Fallback if workspace/shape unsupported -------------------
__global__ __launch_bounds__(T)
void lj_fallback(const float* __restrict__ bv, const int* __restrict__ dst,
                 float* __restrict__ out_energy, float* __restrict__ analytic, int E)
{
    const int e = blockIdx.x * blockDim.x + threadIdx.x;
    float esum = 0.0f;
    if (e < E) {
        float x = bv[3 * e], y = bv[3 * e + 1], z = bv[3 * e + 2];
        float r2 = x * x + y * y + z * z;
        float inv = 1.0f / r2;
        float c6 = inv * inv * inv, c12 = c6 * c6;
        esum = 2.0f * (c12 - c6) + HALF_NEG_E0;
        float fs = -24.0f * (2.0f * c12 - c6) * inv;
        float* p = analytic + 3 * (size_t)dst[e];
        unsafeAtomicAdd(p + 0, fs * x);
        unsafeAtomicAdd(p + 1, fs * y);
        unsafeAtomicAdd(p + 2, fs * z);
    }
#pragma unroll
    for (int off = 32; off > 0; off >>= 1) esum += __shfl_down(esum, off, 64);
    __shared__ float wsum[T / 64];
    if ((threadIdx.x & 63) == 0) wsum[threadIdx.x >> 6] = esum;
    __syncthreads();
    if (threadIdx.x == 0) {
        float s = 0.0f;
        for (int w = 0; w < T / 64; ++w) s += wsum[w];
        unsafeAtomicAdd(out_energy, s);
    }
}

__global__ __launch_bounds__(T)
void lj_scale(const float* __restrict__ analytic, float* __restrict__ forces, int n)
{
    int i = blockIdx.x * blockDim.x + threadIdx.x;
    if (i < n) forces[i] = -0.5f * analytic[i];
}

extern "C" void kernel_launch(void* const* d_in, const int* in_sizes, int n_in,
                              void* d_out, int out_size, void* d_ws, size_t ws_size,
                              hipStream_t stream)
{
    const float* bv  = (const float*)d_in[0];
    const int*   dst = (const int*)d_in[1];
    const int E = in_sizes[0] / 3;
    const int N = (out_size - 1) / 6;   // out = [energy | forces(3N) | analytic(3N)]
    if (E <= 0 || N <= 0) return;

    float* out      = (float*)d_out;
    float* energy   = out;
    float* forces   = out + 1;
    float* analytic = out + 1 + (size_t)3 * N;

    const int NB  = (N + BK - 1) / BK;
    const int G   = (E + 3) / 4;
    const int GPB = (G + B1 - 1) / B1;
    const int capb = GPB * 4;
    const int rpq  = (B1 + Q - 1) / Q;

    auto al = [](size_t x) { return (x + 255) & ~(size_t)255; };
    const size_t sorted_bytes = al((size_t)B1 * capb * 8);
    const size_t bmap_bytes   = al((size_t)B1 * NB * 4);
    const size_t eblk_bytes   = al((size_t)B1 * 4);
    const size_t partXY_bytes = al((size_t)NB * Q * BK * 8);
    const size_t partZ_bytes  = al((size_t)NB * Q * BK * 4);
    const size_t need = sorted_bytes + bmap_bytes + eblk_bytes
                      + partXY_bytes + partZ_bytes;

    // p3 smem ints: s_ent(2*capb) + lcur(4*NB)
    const size_t smem_bytes = (size_t)capb * 8 + (size_t)4 * NB * 4;

    if (NB <= 128 && capb >= 128 && capb < 32768 && GPB <= 3 * T
        && rpq <= RPQ_MAX && smem_bytes <= 64000 && ws_size >= need) {
        char* w = (char*)d_ws;
        int2*               sorted = (int2*)w;               w += sorted_bytes;
        int*                bmap   = (int*)w;                w += bmap_bytes;
        float*              eblk   = (float*)w;              w += eblk_bytes;
        unsigned long long* partXY = (unsigned long long*)w; w += partXY_bytes;
        int*                partZ  = (int*)w;

        p3_fused   <<<B1, T, smem_bytes, stream>>>(bv, dst, bmap, sorted, eblk,
                                                   E, NB, GPB, capb);
        p4a_partial<<<NB * Q, T, 0, stream>>>(sorted, bmap, partXY, partZ,
                                              NB, B1, capb, rpq);
        p4b_merge  <<<(N + T - 1) / T, T, 0, stream>>>(partXY, partZ, eblk,
                                                       forces, analytic, energy,
                                                       N, B1);
    } else {
        hipMemsetAsync(d_out, 0, (size_t)out_size * sizeof(float), stream);
        lj_fallback<<<(E + T - 1) / T, T, 0, stream>>>(bv, dst, energy, analytic, E);
        const int n3 = 3 * N;
        lj_scale<<<(n3 + T - 1) / T, T, 0, stream>>>(analytic, forces, n3);
    }
}

// Round 13
// 165.333 us; speedup vs baseline: 1.0145x; 1.0145x over previous
//
#include <hip/hip_runtime.h>
#include <math.h>

// e0 = 4*((1/3)^12 - (1/3)^6); 0.5*pe = 2*(c12 - c6) - 0.5*e0
static constexpr float HALF_NEG_E0 = 2.739720872e-3f; // -0.5*e0

#define T 256           // threads per block
#define SHIFT 10
#define BK 1024         // nodes per bucket (lid fits in 10 bits)
#define Q 16            // gather sub-blocks per bucket in p4a
#define RPQ_MAX 512     // max runs per p4a block
#define FPSCALE 512.0f  // |f| <= 59.5 -> |int| <= 30450 < 32767
#define INV_FPSCALE (1.0f / 512.0f)

// ---- Phase 3: deterministic staging (NO global atomics, NO memsets).
//      R13: ONE group (4 edges) per thread, GPB=256 -> smem ~9.8 KB ->
//      8 blocks/CU (vs 4). Wave-private histograms+cursors lcur[4][NB].
__global__ __launch_bounds__(T)
void p3_fused(const float* __restrict__ bv, const int* __restrict__ dst,
              int* __restrict__ bmap, int2* __restrict__ sorted,
              float* __restrict__ eblk, int E, int NB, int GPB, int capb)
{
    extern __shared__ int smem[];
    int2* s_ent = (int2*)smem;                    // [capb]
    int*  lcur  = smem + 2 * capb;                // [4][NB] wave-private
    __shared__ int   wtot[4];
    __shared__ float wsum[4];

    const int r = blockIdx.x;
    const int t = threadIdx.x;
    const int wid = t >> 6, lane = t & 63;

    const int G  = (E + 3) >> 2;
    const int gs = r * GPB;
    const int ge = min(G, gs + GPB);
    const int4*   __restrict__ d4  = (const int4*)dst;
    const float4* __restrict__ bv4 = (const float4*)bv;

    // exactly one group per thread (launcher guards GPB <= T)
    const int g0 = gs + t;
    const bool v0 = g0 < ge;
    const bool f0 = v0 && ((g0 << 2) + 3 < E);

    int4 dA;
    if (f0) dA = d4[g0];

    for (int i = t; i < 4 * NB; i += T) lcur[i] = 0;
    __syncthreads();

    // ---- pass A: histogram into this wave's private copy -------------------
    int* myc = lcur + wid * NB;
    if (f0) {
        atomicAdd(&myc[((unsigned)dA.x) >> SHIFT], 1);
        atomicAdd(&myc[((unsigned)dA.y) >> SHIFT], 1);
        atomicAdd(&myc[((unsigned)dA.z) >> SHIFT], 1);
        atomicAdd(&myc[((unsigned)dA.w) >> SHIFT], 1);
    } else if (v0) {
        for (int e = g0 << 2; e < E; ++e)
            atomicAdd(&myc[((unsigned)dst[e]) >> SHIFT], 1);
    }
    __syncthreads();

    // ---- exclusive scan over 4*NB values, bucket-major j = b*4 + w ---------
    {
        const int j0 = 2 * t, j1 = 2 * t + 1;
        const int M  = 4 * NB;
        int va = (j0 < M) ? lcur[(j0 & 3) * NB + (j0 >> 2)] : 0;
        int vb = (j1 < M) ? lcur[(j1 & 3) * NB + (j1 >> 2)] : 0;
        int s = va + vb;
        int incl = s;
#pragma unroll
        for (int off = 1; off < 64; off <<= 1) {
            int u = __shfl_up(incl, off, 64);
            if (lane >= off) incl += u;
        }
        if (lane == 63) wtot[wid] = incl;
        __syncthreads();
        int wpre = 0;
#pragma unroll
        for (int w = 0; w < 4; ++w) wpre += (w < wid) ? wtot[w] : 0;
        int ex0 = wpre + incl - s;
        if (j0 < M) lcur[(j0 & 3) * NB + (j0 >> 2)] = ex0;
        if (j1 < M) lcur[(j1 & 3) * NB + (j1 >> 2)] = ex0 + va;
    }
    __syncthreads();

    // ---- write run directory from bucket starts (w=0 slots) ----------------
    const int nloc = max(0, min(E, ge << 2) - (gs << 2));
    if (t < NB) {
        int st = lcur[t];                         // ex(b, w=0) = region start
        int en = (t + 1 < NB) ? lcur[t + 1] : nloc;
        bmap[(size_t)r * NB + t] = st | ((en - st) << 16);
    }
    __syncthreads();

    // ---- pass B: compute + stage via wave-private cursors ------------------
    float esum = 0.0f;

    auto edge1 = [&](float x, float y, float z, int node) {
        float r2  = x * x + y * y + z * z;
        float inv = 1.0f / r2;
        float c6  = inv * inv * inv;
        float c12 = c6 * c6;
        esum += 2.0f * (c12 - c6) + HALF_NEG_E0;
        float fs = -24.0f * (2.0f * c12 - c6) * inv * FPSCALE;
        int ix = __float2int_rn(fs * x);
        int iy = __float2int_rn(fs * y);
        int iz = __float2int_rn(fs * z);
        int b  = ((unsigned)node) >> SHIFT;
        int slot = atomicAdd(&myc[b], 1);         // wave-private cursor
        s_ent[slot] = make_int2((ix & 0xffff) | (iy << 16),
                                (iz & 0xffff) | ((node & (BK - 1)) << 16));
    };

    if (f0) {
        float4 a = bv4[3 * g0], b2 = bv4[3 * g0 + 1], c = bv4[3 * g0 + 2];
        edge1(a.x, a.y, a.z, dA.x);
        edge1(a.w, b2.x, b2.y, dA.y);
        edge1(b2.z, b2.w, c.x, dA.z);
        edge1(c.y, c.z, c.w, dA.w);
    } else if (v0) {
        for (int e = g0 << 2; e < E; ++e)
            edge1(bv[3 * e], bv[3 * e + 1], bv[3 * e + 2], dst[e]);
    }
    __syncthreads();

    // ---- flush: int4 pairs, contiguous coalesced write to own region -------
    {
        const int nh = nloc >> 1;
        const int4* se4 = (const int4*)s_ent;
        int4* so4 = (int4*)(sorted + (size_t)r * capb);   // capb even -> 16B
        for (int i = t; i < nh; i += T) so4[i] = se4[i];
        if ((nloc & 1) && t == 0)
            sorted[(size_t)r * capb + nloc - 1] = s_ent[nloc - 1];
    }

    // ---- energy: wave shuffle -> LDS -> one plain store per block ----------
#pragma unroll
    for (int off = 32; off > 0; off >>= 1)
        esum += __shfl_down(esum, off, 64);
    if (lane == 0) wsum[wid] = esum;
    __syncthreads();
    if (t == 0) {
        float s = 0.0f;
        for (int w = 0; w < 4; ++w) s += wsum[w];
        eblk[r] = s;
    }
}

// ---- Phase 4a: bucket-major partial reduce over a run-subrange -------------
// Quarter-wave-per-run gather, packed u64 LDS accumulate, deterministic
// int partials. Q=16 -> 1568 blocks (~6/CU, 24 waves/CU).
__global__ __launch_bounds__(T)
void p4a_partial(const int2* __restrict__ sorted, const int* __restrict__ bmap,
                 unsigned long long* __restrict__ partXY, int* __restrict__ partZ,
                 int NB, int nblk, int capb, int rpq)
{
    __shared__ unsigned long long accXY[BK];      // 8 KB
    __shared__ int accZ[BK];                      // 4 KB
    __shared__ int runsL[RPQ_MAX];                // run directory slice

    const int b = blockIdx.x / Q;
    const int q = blockIdx.x - b * Q;
    const int t = threadIdx.x;

    const int rbeg = q * rpq;
    const int rend = min(nblk, rbeg + rpq);
    const int nr   = rend - rbeg;

    for (int i = t; i < BK; i += T) { accXY[i] = 0ull; accZ[i] = 0; }
    for (int i = t; i < nr; i += T) runsL[i] = bmap[(size_t)(rbeg + i) * NB + b];
    __syncthreads();

    const int wid  = t >> 6;
    const int lane = t & 63;
    const int sub  = lane >> 4;   // quarter-wave id 0..3
    const int l16  = lane & 15;

    for (int rr = 4 * wid; rr < nr; rr += 16) {
        const int ri = rr + sub;
        if (ri < nr) {
            const int m   = runsL[ri];
            const int cnt = m >> 16;
            const int2* src = sorted + (size_t)(rbeg + ri) * capb + (m & 0xffff);
            for (int c = l16; c < cnt; c += 16) {
                int2 v = src[c];
                int lid = ((unsigned)v.y) >> 16;
                unsigned long long p =
                    ((unsigned long long)(unsigned)(v.x >> 16) << 32)
                  + (unsigned long long)(long long)(int)(short)(v.x & 0xffff);
                atomicAdd(&accXY[lid], p);
                atomicAdd(&accZ[lid], (int)(short)(v.y & 0xffff));
            }
        }
    }
    __syncthreads();
    unsigned long long* PX = partXY + (size_t)blockIdx.x * BK;
    int*                PZ = partZ  + (size_t)blockIdx.x * BK;
    for (int i = t; i < BK; i += T) { PX[i] = accXY[i]; PZ[i] = accZ[i]; }
}

// ---- Phase 4b: merge Q packed partials per node, decode, write outputs -----
__global__ __launch_bounds__(T)
void p4b_merge(const unsigned long long* __restrict__ partXY,
               const int* __restrict__ partZ, const float* __restrict__ eblk,
               float* __restrict__ forces, float* __restrict__ analytic,
               float* __restrict__ energy, int N, int nblk)
{
    __shared__ float ws[T / 64];
    const int t = threadIdx.x;

    if (blockIdx.x == 0) {
        float es = 0.0f;
        for (int i = t; i < nblk; i += T) es += eblk[i];
#pragma unroll
        for (int off = 32; off > 0; off >>= 1)
            es += __shfl_down(es, off, 64);
        if ((t & 63) == 0) ws[t >> 6] = es;
        __syncthreads();
        if (t == 0) {
            float s = 0.0f;
            for (int w = 0; w < T / 64; ++w) s += ws[w];
            energy[0] = s;
        }
    }

    const int node = blockIdx.x * T + t;
    if (node >= N) return;
    const int b   = node >> SHIFT;
    const int lid = node & (BK - 1);
    const unsigned long long* PX = partXY + ((size_t)b * Q) * BK + lid;
    const int*                PZ = partZ  + ((size_t)b * Q) * BK + lid;
    unsigned long long sxy = 0ull; int sz = 0;
#pragma unroll
    for (int qq = 0; qq < Q; ++qq) {
        sxy += PX[(size_t)qq * BK];
        sz  += PZ[(size_t)qq * BK];
    }
    int sx = (int)(unsigned)(sxy & 0xffffffffull);
    int sy = (int)(unsigned)(sxy >> 32) + (sx < 0 ? 1 : 0);
    float vx = (float)sx * INV_FPSCALE;
    float vy = (float)sy * INV_FPSCALE;
    float vz = (float)sz * INV_FPSCALE;
    analytic[3 * node + 0] = vx;
    analytic[3 * node + 1] = vy;
    analytic[3 * node + 2] = vz;
    forces[3 * node + 0] = -0.5f * vx;
    forces[3 * node + 1] = -0.5f * vy;
    forces[3 * node + 2] = -0.5f * vz;
}

// ---------------- Fallback if workspace/shape unsupported -------------------
__global__ __launch_bounds__(T)
void lj_fallback(const float* __restrict__ bv, const int* __restrict__ dst,
                 float* __restrict__ out_energy, float* __restrict__ analytic, int E)
{
    const int e = blockIdx.x * blockDim.x + threadIdx.x;
    float esum = 0.0f;
    if (e < E) {
        float x = bv[3 * e], y = bv[3 * e + 1], z = bv[3 * e + 2];
        float r2 = x * x + y * y + z * z;
        float inv = 1.0f / r2;
        float c6 = inv * inv * inv, c12 = c6 * c6;
        esum = 2.0f * (c12 - c6) + HALF_NEG_E0;
        float fs = -24.0f * (2.0f * c12 - c6) * inv;
        float* p = analytic + 3 * (size_t)dst[e];
        unsafeAtomicAdd(p + 0, fs * x);
        unsafeAtomicAdd(p + 1, fs * y);
        unsafeAtomicAdd(p + 2, fs * z);
    }
#pragma unroll
    for (int off = 32; off > 0; off >>= 1) esum += __shfl_down(esum, off, 64);
    __shared__ float wsum[T / 64];
    if ((threadIdx.x & 63) == 0) wsum[threadIdx.x >> 6] = esum;
    __syncthreads();
    if (threadIdx.x == 0) {
        float s = 0.0f;
        for (int w = 0; w < T / 64; ++w) s += wsum[w];
        unsafeAtomicAdd(out_energy, s);
    }
}

__global__ __launch_bounds__(T)
void lj_scale(const float* __restrict__ analytic, float* __restrict__ forces, int n)
{
    int i = blockIdx.x * blockDim.x + threadIdx.x;
    if (i < n) forces[i] = -0.5f * analytic[i];
}

extern "C" void kernel_launch(void* const* d_in, const int* in_sizes, int n_in,
                              void* d_out, int out_size, void* d_ws, size_t ws_size,
                              hipStream_t stream)
{
    const float* bv  = (const float*)d_in[0];
    const int*   dst = (const int*)d_in[1];
    const int E = in_sizes[0] / 3;
    const int N = (out_size - 1) / 6;   // out = [energy | forces(3N) | analytic(3N)]
    if (E <= 0 || N <= 0) return;

    float* out      = (float*)d_out;
    float* energy   = out;
    float* forces   = out + 1;
    float* analytic = out + 1 + (size_t)3 * N;

    const int NB = (N + BK - 1) / BK;
    const int G  = (E + 3) / 4;
    // one group (4 edges) per thread
    int B1 = (G + T - 1) / T;
    if (B1 < 1) B1 = 1;
    const int GPB = (G + B1 - 1) / B1;
    const int capb = GPB * 4;
    const int rpq  = (B1 + Q - 1) / Q;

    auto al = [](size_t x) { return (x + 255) & ~(size_t)255; };
    const size_t sorted_bytes = al((size_t)B1 * capb * 8);
    const size_t bmap_bytes   = al((size_t)B1 * NB * 4);
    const size_t eblk_bytes   = al((size_t)B1 * 4);
    const size_t partXY_bytes = al((size_t)NB * Q * BK * 8);
    const size_t partZ_bytes  = al((size_t)NB * Q * BK * 4);
    const size_t need = sorted_bytes + bmap_bytes + eblk_bytes
                      + partXY_bytes + partZ_bytes;

    // p3 smem ints: s_ent(2*capb) + lcur(4*NB)
    const size_t smem_bytes = (size_t)capb * 8 + (size_t)4 * NB * 4;

    if (NB <= 128 && capb >= 128 && capb < 32768 && GPB <= T
        && rpq <= RPQ_MAX && smem_bytes <= 64000 && ws_size >= need) {
        char* w = (char*)d_ws;
        int2*               sorted = (int2*)w;               w += sorted_bytes;
        int*                bmap   = (int*)w;                w += bmap_bytes;
        float*              eblk   = (float*)w;              w += eblk_bytes;
        unsigned long long* partXY = (unsigned long long*)w; w += partXY_bytes;
        int*                partZ  = (int*)w;

        p3_fused   <<<B1, T, smem_bytes, stream>>>(bv, dst, bmap, sorted, eblk,
                                                   E, NB, GPB, capb);
        p4a_partial<<<NB * Q, T, 0, stream>>>(sorted, bmap, partXY, partZ,
                                              NB, B1, capb, rpq);
        p4b_merge  <<<(N + T - 1) / T, T, 0, stream>>>(partXY, partZ, eblk,
                                                       forces, analytic, energy,
                                                       N, B1);
    } else {
        hipMemsetAsync(d_out, 0, (size_t)out_size * sizeof(float), stream);
        lj_fallback<<<(E + T - 1) / T, T, 0, stream>>>(bv, dst, energy, analytic, E);
        const int n3 = 3 * N;
        lj_scale<<<(n3 + T - 1) / T, T, 0, stream>>>(analytic, forces, n3);
    }
}